// Round 8
// baseline (189.664 us; speedup 1.0000x reference)
//
#include <hip/hip_runtime.h>
#include <hip/hip_bf16.h>
#include <stdint.h>

typedef float v4f __attribute__((ext_vector_type(4)));
typedef short v8s __attribute__((ext_vector_type(8)));
typedef short v4s __attribute__((ext_vector_type(4)));

#define LOG2E 1.44269504088896f
#define QSCALE (0.125f * LOG2E)   // fold softmax log2-domain into Q pre-scale
#define SOFTMAX_OFF 16.0f         // fixed softmax offset (exact; cancels in O/l)

__device__ __forceinline__ unsigned short f2bf(float f) {
    unsigned int u = __float_as_uint(f);
    u += 0x7fffu + ((u >> 16) & 1u);          // RTNE
    return (unsigned short)(u >> 16);
}

// Compiler+HW LDS ordering fence for intra-wave LDS write->read exchange.
#define LDS_FENCE() __builtin_amdgcn_fence(__ATOMIC_ACQ_REL, "workgroup")

// async global->LDS, 16B per lane, LDS dest = wave-uniform base + lane*16
__device__ __forceinline__ void gload_lds16(const unsigned short* g, unsigned short* s) {
    __builtin_amdgcn_global_load_lds(
        (const __attribute__((address_space(1))) unsigned int*)g,
        (__attribute__((address_space(3))) unsigned int*)s, 16, 0, 0);
}

// barriers with memory clobber: loads may not be hoisted/sunk across
#define BAR()      asm volatile("s_barrier" ::: "memory")
#define VMWAIT(N)  asm volatile("s_waitcnt vmcnt(" #N ")" ::: "memory")

#define PIPE_BARRIER_KEEP4()                                   \
    do {                                                       \
        asm volatile("s_waitcnt vmcnt(4)" ::: "memory");       \
        __builtin_amdgcn_s_barrier();                          \
        asm volatile("" ::: "memory");                         \
    } while (0)
#define PIPE_BARRIER_DRAIN()                                   \
    do {                                                       \
        asm volatile("s_waitcnt vmcnt(0)" ::: "memory");       \
        __builtin_amdgcn_s_barrier();                          \
        asm volatile("" ::: "memory");                         \
    } while (0)

// ---------------- prep: cast + rope table + both weight transposes ----------------
__global__ void k_prep(const float* __restrict__ x,
                       const float* __restrict__ w_qkv,
                       const float* __restrict__ w_out,
                       unsigned short* __restrict__ xb,
                       unsigned short* __restrict__ wqkvT,
                       unsigned short* __restrict__ woutT,
                       float2* __restrict__ rope) {
    __shared__ unsigned short tile[64][65];
    int id = blockIdx.x, t = threadIdx.x;
    if (id < 1024) {
        int base = id * 256 + t;
#pragma unroll
        for (int k = 0; k < 4; ++k) {
            int i = base + k * 262144;
            float4 v = ((const float4*)x)[i];
            ushort4 o;
            o.x = f2bf(v.x); o.y = f2bf(v.y); o.z = f2bf(v.z); o.w = f2bf(v.w);
            ((ushort4*)xb)[i] = o;
        }
        return;
    }
    id -= 1024;
    if (id < 256) {
        int idx = id * 256 + t;                    // 65536 = 2048 s x 32 d
        int s = idx >> 5, d = idx & 31;
        float inv = __expf(-(float)d * 0.28782313662425572f);  // 10000^(-d/32)
        float sn, cs;
        sincosf((float)s * inv, &sn, &cs);
        rope[idx] = make_float2(cs, sn);
        return;
    }
    id -= 256;
    const float* src; unsigned short* dst; int N, kb, nb;
    if (id < 768) { src = w_qkv; dst = wqkvT; N = 3072; nb = (id % 48) * 64; kb = (id / 48) * 64; }
    else { id -= 768; src = w_out; dst = woutT; N = 1024; nb = (id % 16) * 64; kb = (id / 16) * 64; }
    const int K = 1024;
    for (int i = 0; i < 16; ++i) {
        int e = t + i * 256;
        int n_l = e & 63, k_l = e >> 6;
        tile[n_l][k_l] = f2bf(src[(size_t)(kb + k_l) * N + nb + n_l]);
    }
    __syncthreads();
    for (int i = 0; i < 16; ++i) {
        int e = t + i * 256;
        int k_l = e & 63, n_l = e >> 6;
        dst[(size_t)(nb + n_l) * K + kb + k_l] = tile[n_l][k_l];
    }
}

// ------------- QKV GEMM: 256x256 tile, BK=64, 8 waves, 8-phase, NO sched pinning ----
// Round-8 change: removed all explicit lgkmcnt(0)+sched_barrier(0) (m141: order-pinning
// defeats compiler scheduling; ds_reads here are compiler-tracked pointer loads, so the
// compiler emits its own fine-grained lgkmcnt before each MFMA use).
__global__ __launch_bounds__(512, 2) void k_gemm_qkv(
    const unsigned short* __restrict__ A,
    const unsigned short* __restrict__ Bt,
    const float2* __restrict__ rope,
    unsigned short* __restrict__ Qg,
    unsigned short* __restrict__ Kg,
    unsigned short* __restrict__ Vt) {
    const int K = 1024;
    __shared__ __align__(16) union {
        struct { unsigned short Ab[2][256 * 64], Bb[2][256 * 64]; } g;  // 128 KB
        unsigned short vt[4][64][264];                                  // 132 KB V-transpose
        unsigned short qk[8][128][66];                                  // 132 KB Q/K transpose
    } sm;
    const int t = threadIdx.x;
    const int w = t >> 6, l = t & 63, quad = l >> 4, ln = l & 15;
    const int wr = w >> 2, wc = w & 3;            // wave grid 2M x 4N, 128x64 per wave
    // XCD-aware swizzle: 192 blocks = 8 xcd x 24; bijective (192%8==0).
    const int lid = blockIdx.y * 12 + blockIdx.x;
    const int swzb = (lid & 7) * 24 + (lid >> 3);
    const int mb = (swzb / 12) * 256, nb = (swzb % 12) * 256;
    const int lxr = l >> 3;                       // lane row within 8-row chunk
    const int swz = ((l & 7) ^ lxr) * 8;          // pre-swizzled src col (ushorts)

    v4f acc[8][4];
#pragma unroll
    for (int i = 0; i < 8; ++i)
#pragma unroll
        for (int j = 0; j < 4; ++j) acc[i][j] = (v4f){0.f, 0.f, 0.f, 0.f};

    auto stageHT = [&](const unsigned short* src, int grow, int k0, unsigned short* lds) {
#pragma unroll
        for (int c = 0; c < 2; ++c) {
            int r0 = w * 16 + c * 8;
            gload_lds16(src + (size_t)(grow + r0 + lxr) * K + k0 + swz, lds + r0 * 64);
        }
    };
    auto frag = [&](const unsigned short* base, int row, int g16) -> v8s {
        return *(const v8s*)&base[row * 64 + ((g16 ^ (row & 7)) << 3)];
    };

    v8s aF[4][2], bF0[2][2], bF1[2][2];
    auto readA = [&](const unsigned short* Ap, int ih) {
#pragma unroll
        for (int ii = 0; ii < 4; ++ii) {
            int row = wr * 128 + (ih * 4 + ii) * 16 + ln;
#pragma unroll
            for (int kh = 0; kh < 2; ++kh) aF[ii][kh] = frag(Ap, row, kh * 4 + quad);
        }
    };
    auto readB = [&](const unsigned short* Bp, int jh, v8s (&bF)[2][2]) {
#pragma unroll
        for (int jj = 0; jj < 2; ++jj) {
            int row = wc * 64 + (jh * 2 + jj) * 16 + ln;
#pragma unroll
            for (int kh = 0; kh < 2; ++kh) bF[jj][kh] = frag(Bp, row, kh * 4 + quad);
        }
    };
    auto mfma16 = [&](v8s (&bF)[2][2], int ih, int jh) {
        __builtin_amdgcn_s_setprio(1);
#pragma unroll
        for (int ii = 0; ii < 4; ++ii)
#pragma unroll
            for (int jj = 0; jj < 2; ++jj) {
                v4f* ac = &acc[ih * 4 + ii][jh * 2 + jj];
                *ac = __builtin_amdgcn_mfma_f32_16x16x32_bf16(aF[ii][0], bF[jj][0], *ac, 0, 0, 0);
                *ac = __builtin_amdgcn_mfma_f32_16x16x32_bf16(aF[ii][1], bF[jj][1], *ac, 0, 0, 0);
            }
        __builtin_amdgcn_s_setprio(0);
    };

    const unsigned short* Ap0 = &sm.g.Ab[0][0];
    const unsigned short* Ap1 = &sm.g.Ab[1][0];
    const unsigned short* Bp0 = &sm.g.Bb[0][0];
    const unsigned short* Bp1 = &sm.g.Bb[1][0];

    // prologue: tile0 (A,B) + B(1); vmcnt(4) keeps B(1) in flight
    stageHT(A,  mb,       0,  &sm.g.Ab[0][0]);
    stageHT(A,  mb + 128, 0,  &sm.g.Ab[0][128 * 64]);
    stageHT(Bt, nb,       0,  &sm.g.Bb[0][0]);
    stageHT(Bt, nb + 128, 0,  &sm.g.Bb[0][128 * 64]);
    stageHT(Bt, nb,       64, &sm.g.Bb[1][0]);
    stageHT(Bt, nb + 128, 64, &sm.g.Bb[1][128 * 64]);
    VMWAIT(4);
    BAR();

    for (int it = 0; it < 8; ++it) {
        const int c1k = (2 * it + 1) * 64, n0k = (2 * it + 2) * 64, n1k = (2 * it + 3) * 64;
        const bool pre = it < 7;
        // ---- P0: reads A03+B01 of c0 | stage A-lo(c1)
        readA(Ap0, 0); readB(Bp0, 0, bF0);
        stageHT(A, mb, c1k, &sm.g.Ab[1][0]);
        BAR();
        mfma16(bF0, 0, 0);
        BAR();
        // ---- P1: reads B23 of c0 | stage A-hi(c1)
        readB(Bp0, 1, bF1);
        stageHT(A, mb + 128, c1k, &sm.g.Ab[1][128 * 64]);
        BAR();
        mfma16(bF1, 0, 1);
        BAR();
        // ---- P2: reads A47 of c0 | stage B-lo(c0+2)
        readA(Ap0, 1);
        if (pre) stageHT(Bt, nb, n0k, &sm.g.Bb[0][0]);
        BAR();
        mfma16(bF0, 1, 0);
        BAR();
        // ---- P3: no reads | stage B-hi(c0+2) | vmcnt: tile c1 landed
        if (pre) stageHT(Bt, nb + 128, n0k, &sm.g.Bb[0][128 * 64]);
        BAR();
        mfma16(bF1, 1, 1);
        if (pre) VMWAIT(4); else VMWAIT(0);
        BAR();
        // ---- P4: reads A03+B01 of c1 | stage A-lo(c0+2)
        readA(Ap1, 0); readB(Bp1, 0, bF0);
        if (pre) stageHT(A, mb, n0k, &sm.g.Ab[0][0]);
        BAR();
        mfma16(bF0, 0, 0);
        BAR();
        // ---- P5: reads B23 of c1 | stage A-hi(c0+2)
        readB(Bp1, 1, bF1);
        if (pre) stageHT(A, mb + 128, n0k, &sm.g.Ab[0][128 * 64]);
        BAR();
        mfma16(bF1, 0, 1);
        BAR();
        // ---- P6: reads A47 of c1 | stage B-lo(c1+2)
        readA(Ap1, 1);
        if (pre) stageHT(Bt, nb, n1k, &sm.g.Bb[1][0]);
        BAR();
        mfma16(bF0, 1, 0);
        BAR();
        // ---- P7: no reads | stage B-hi(c1+2) | vmcnt: tile c0+2 landed
        if (pre) stageHT(Bt, nb + 128, n1k, &sm.g.Bb[1][128 * 64]);
        BAR();
        mfma16(bF1, 1, 1);
        if (pre) VMWAIT(4);
        BAR();
    }

    if (nb >= 2048) {                              // ---- V: LDS transpose epilogue
        __syncthreads();
#pragma unroll
        for (int i = 0; i < 8; ++i)
#pragma unroll
            for (int j = 0; j < 4; ++j) {
                int d = j * 16 + ln;
                int s0 = wr * 128 + i * 16 + quad * 4;
                ushort4 pk;
                pk.x = f2bf(acc[i][j][0]); pk.y = f2bf(acc[i][j][1]);
                pk.z = f2bf(acc[i][j][2]); pk.w = f2bf(acc[i][j][3]);
                *(ushort4*)&sm.vt[wc][d][s0] = pk;
            }
        __syncthreads();
        const int hbase = (nb & 1023) >> 6;
        const int b = mb >> 11, sbase = mb & 2047;
#pragma unroll
        for (int i = 0; i < 16; ++i) {
            int c = t + i * 512;                   // 8192 chunks of 16B
            int h2 = c >> 11, dd = (c >> 5) & 63, off = (c & 31) * 8;
            v8s val = *(const v8s*)&sm.vt[h2][dd][off];
            *(v8s*)(Vt + ((size_t)((b * 16 + hbase + h2) * 64 + dd) * 2048 + sbase + off)) = val;
        }
        return;
    }

    // ---- Q/K: rope in-register -> wave-private LDS tile -> coalesced 16B stores
    const int nbw = nb + wc * 64;
    const int region = nbw >> 10;                  // 0=Q, 1=K
    const int h = (nbw & 1023) >> 6;
    unsigned short* dst = region == 0 ? Qg : Kg;
    const float scale = region == 0 ? QSCALE : 1.0f;
    unsigned short* qkw = &sm.qk[w][0][0];         // wave-private [128][66]
#pragma unroll
    for (int jj = 0; jj < 2; ++jj) {
        const float2* rp = rope + jj * 16 + ln;
#pragma unroll
        for (int i = 0; i < 8; ++i)
#pragma unroll
            for (int r = 0; r < 4; ++r) {
                int lr = i * 16 + quad * 4 + r;
                int s = (mb + wr * 128 + lr) & 2047;
                float2 cs = rp[s * 32];
                float t1 = acc[i][jj][r], t2 = acc[i][jj + 2][r];
                qkw[lr * 66 + jj * 16 + ln]      = f2bf((t1 * cs.x - t2 * cs.y) * scale);
                qkw[lr * 66 + jj * 16 + ln + 32] = f2bf((t2 * cs.x + t1 * cs.y) * scale);
            }
    }
    LDS_FENCE();
    const int row0 = mb + wr * 128;
    const int bb = row0 >> 11, s0 = row0 & 2047;
    unsigned short* gbase = dst + ((size_t)(bb * 16 + h) * 2048 + s0) * 64;
#pragma unroll
    for (int itn = 0; itn < 16; ++itn) {
        int c = itn * 64 + l;                      // 1024 chunks of 16B (128 rows x 8)
        int lr = c >> 3, off = (c & 7) * 8;
        v8s val = *(const v8s*)&qkw[lr * 66 + off];
        *(v8s*)(gbase + (size_t)lr * 64 + off) = val;
    }
}

// ------------- output projection GEMM, 3-buffer counted-vmcnt pipeline, f32 out -------------
__global__ __launch_bounds__(256) void k_gemm_out(
    const unsigned short* __restrict__ A,      // Og [4096][1024]
    const unsigned short* __restrict__ Bt,     // woutT [1024][1024]
    float* __restrict__ C) {
    const int K = 1024, N = 1024;
    __shared__ __align__(16) unsigned short Ab[3][4096];
    __shared__ __align__(16) unsigned short Bb[3][4096];
    const int t = threadIdx.x;
    const int w = t >> 6, l = t & 63, quad = l >> 4, ln = l & 15;
    const int wm = (w >> 1) * 64, wn = (w & 1) * 64;
    const int mb = blockIdx.y * 128, nb = blockIdx.x * 128;

    v4f acc[4][4];
#pragma unroll
    for (int i = 0; i < 4; ++i)
#pragma unroll
        for (int j = 0; j < 4; ++j) acc[i][j] = (v4f){0.f, 0.f, 0.f, 0.f};

    auto stage = [&](int buf, int k0) {
#pragma unroll
        for (int u = 0; u < 2; ++u) {
            int e = t + u * 256;
            gload_lds16(A + (size_t)(mb + (e >> 2)) * K + k0 + (e & 3) * 8,
                        &Ab[buf][(w * 64 + u * 256) * 8]);
            gload_lds16(Bt + (size_t)(nb + (e >> 2)) * K + k0 + (e & 3) * 8,
                        &Bb[buf][(w * 64 + u * 256) * 8]);
        }
    };

    stage(0, 0);
    stage(1, 32);
    int cur = 0, nxt = 2;
    for (int itk = 0; itk < 32; ++itk) {
        if (itk < 31) PIPE_BARRIER_KEEP4();
        else          PIPE_BARRIER_DRAIN();
        if (itk + 2 < 32) {
            stage(nxt, (itk + 2) * 32);
            nxt = nxt == 2 ? 0 : nxt + 1;
        }
        v8s af[4], bfr[4];
#pragma unroll
        for (int i = 0; i < 4; ++i)
            af[i] = *(const v8s*)&Ab[cur][(wm + i * 16 + ln) * 32 + quad * 8];
#pragma unroll
        for (int j = 0; j < 4; ++j)
            bfr[j] = *(const v8s*)&Bb[cur][(wn + j * 16 + ln) * 32 + quad * 8];
#pragma unroll
        for (int i = 0; i < 4; ++i)
#pragma unroll
            for (int j = 0; j < 4; ++j)
                acc[i][j] = __builtin_amdgcn_mfma_f32_16x16x32_bf16(
                    af[i], bfr[j], acc[i][j], 0, 0, 0);
        cur = cur == 2 ? 0 : cur + 1;
    }

#pragma unroll
    for (int i = 0; i < 4; ++i) {
        int r0 = mb + wm + i * 16 + quad * 4;
#pragma unroll
        for (int j = 0; j < 4; ++j) {
            int c0 = nb + wn + j * 16 + ln;
#pragma unroll
            for (int r = 0; r < 4; ++r)
                C[(size_t)(r0 + r) * N + c0] = acc[i][j][r];
        }
    }
}

// ------------- causal flash attention, v13: in-register P + b128 V-reads -------------
// v12's ds_read_b64 V-reads measured 4.3M bank conflicts; the scattered-row b128
// pattern measured 0 (r6).  Read the full 16B granule and select the (quad&1)
// half in-register (2 v_cndmask per read).
__global__ __launch_bounds__(256, 4) void k_flash(
    const unsigned short* __restrict__ Qg,   // [BH][S][64], scaled 0.125*log2e
    const unsigned short* __restrict__ Kg,   // [BH][S][64]
    const unsigned short* __restrict__ Vt,   // [BH][64][S]
    unsigned short* __restrict__ Og) {       // [B*S][1024]
    __shared__ __align__(16) unsigned short Kb[2][64 * 64];
    __shared__ __align__(16) unsigned short Vb[2][64 * 64];

    const int id = blockIdx.x;
    const int xcd = id & 7, slot = id >> 3;
    const int bh = xcd * 4 + (slot & 3);
    const int qt = 31 - (slot >> 2);                 // heavy tiles first
    const int qbase = qt * 64;
    const int nit = qt + 1;

    const int t = threadIdx.x, w = t >> 6, l = t & 63, quad = l >> 4, ln = l & 15;
    const int b = bh >> 4, h = bh & 15;

    const unsigned short* Qp = Qg + (size_t)bh * 2048 * 64;
    const unsigned short* Kp = Kg + (size_t)bh * 2048 * 64;
    const unsigned short* Vp = Vt + (size_t)bh * 64 * 2048;

    unsigned kst[2], vst[2];
    int cchunk = l & 7, rloc = l >> 3;
#pragma unroll
    for (int j = 0; j < 2; ++j) {
        int c = w + j * 4;
        int rr = c * 8 + rloc;
        int g = (cchunk + rr) & 7;
        kst[j] = (unsigned)(rr * 64 + g * 8);
        vst[j] = (unsigned)(rr * 2048 + g * 8);
    }
    const int c0 = ((quad - ln) & 7) * 8;            // K-row granule decode (d 0..31)
    const int c1 = ((quad + 4 - ln) & 7) * 8;        // (d 32..63)
    // V granule chunk per kt (shorts): row rotation (gg - row)&7, gg = kt*2+(quad>>1)
    int vch[4];
#pragma unroll
    for (int kt = 0; kt < 4; ++kt)
        vch[kt] = ((kt * 2 + (quad >> 1) - ln) & 7) * 8;
    const v4s ones4 = {0x3F80, 0x3F80, 0x3F80, 0x3F80};

    const int qrow = qbase + w * 16 + ln;
    v8s qf0 = *(const v8s*)(Qp + (size_t)qrow * 64 + quad * 8);
    v8s qf1 = *(const v8s*)(Qp + (size_t)qrow * 64 + quad * 8 + 32);

    v4f oacc[5];
#pragma unroll
    for (int dt = 0; dt < 5; ++dt) oacc[dt] = (v4f){0.f, 0.f, 0.f, 0.f};

    auto stage = [&](int buf, int kvb) {
        const unsigned short* kg = Kp + (size_t)kvb * 64;
        const unsigned short* vg = Vp + kvb;
#pragma unroll
        for (int j = 0; j < 2; ++j) {
            int c = w + j * 4;
            gload_lds16(kg + kst[j], &Kb[buf][c * 512]);
            gload_lds16(vg + vst[j], &Vb[buf][c * 512]);
        }
    };

    auto compute = [&](int buf, int it) {
        // QK^T swapped: A=K rows (m = local k-row), B=Q (n = q)
        v4f sc[4];
#pragma unroll
        for (int kt = 0; kt < 4; ++kt) {
            int row = kt * 16 + ln;
            v8s k0 = *(const v8s*)&Kb[buf][row * 64 + c0];
            v8s k1 = *(const v8s*)&Kb[buf][row * 64 + c1];
            sc[kt] = (v4f){0.f, 0.f, 0.f, 0.f};
            sc[kt] = __builtin_amdgcn_mfma_f32_16x16x32_bf16(k0, qf0, sc[kt], 0, 0, 0);
            sc[kt] = __builtin_amdgcn_mfma_f32_16x16x32_bf16(k1, qf1, sc[kt], 0, 0, 0);
        }
        if (it == qt) {                              // causal: k = kt*16+quad*4+r, q = w*16+ln
            int qg = w * 16 + ln;
#pragma unroll
            for (int kt = 0; kt < 4; ++kt) {
                int kv = kt * 16 + quad * 4;
#pragma unroll
                for (int r = 0; r < 4; ++r)
                    if (kv + r > qg) sc[kt][r] = -1e30f;
            }
        }
#pragma unroll
        for (int kt = 0; kt < 4; ++kt)
#pragma unroll
            for (int r = 0; r < 4; ++r)
                sc[kt][r] = exp2f(sc[kt][r] - SOFTMAX_OFF);

        // pack: pa[kt] = P[q=ln][k=kt*16+quad*4 + 0..3] = x16 A-fragment, in-register
        v4s pa[4];
#pragma unroll
        for (int kt = 0; kt < 4; ++kt) {
            union { __hip_bfloat162 hh; unsigned int u; } p01, p23;
            p01.hh = __float22bfloat162_rn(make_float2(sc[kt][0], sc[kt][1]));
            p23.hh = __float22bfloat162_rn(make_float2(sc[kt][2], sc[kt][3]));
            union { v4s v; unsigned int u[2]; } pk;
            pk.u[0] = p01.u; pk.u[1] = p23.u;
            pa[kt] = pk.v;
        }
        __builtin_amdgcn_s_setprio(1);
#pragma unroll
        for (int dt = 0; dt < 4; ++dt) {
            int rowb = (dt * 16 + ln) * 64;
#pragma unroll
            for (int kt = 0; kt < 4; ++kt) {
                v8s vv = *(const v8s*)&Vb[buf][rowb + vch[kt]];
                v4s lo = __builtin_shufflevector(vv, vv, 0, 1, 2, 3);
                v4s hi = __builtin_shufflevector(vv, vv, 4, 5, 6, 7);
                v4s vf = (quad & 1) ? hi : lo;
                oacc[dt] = __builtin_amdgcn_mfma_f32_16x16x16bf16_1k(pa[kt], vf, oacc[dt], 0, 0, 0);
            }
        }
#pragma unroll
        for (int kt = 0; kt < 4; ++kt)
            oacc[4] = __builtin_amdgcn_mfma_f32_16x16x16bf16_1k(pa[kt], ones4, oacc[4], 0, 0, 0);
        __builtin_amdgcn_s_setprio(0);
    };

    // counted pipeline: stage(next) stays in flight across the barrier
    stage(0, 0);
    for (int it = 0;;) {
        const int buf = it & 1;
        stage(buf ^ 1, (it + 1) * 64);   // prefetch next tile (over-reads are in-workspace)
        VMWAIT(4);                       // wait own stage(buf); stage(buf^1) stays in flight
        BAR();                           // all waves' stage(buf) landed
        compute(buf, it);
        if (++it >= nit) break;
        BAR();                           // readers of buf done before overwrite
    }

    float rden[4];
#pragma unroll
    for (int r = 0; r < 4; ++r) rden[r] = 1.f / oacc[4][r];
#pragma unroll
    for (int dt = 0; dt < 4; ++dt)
#pragma unroll
        for (int r = 0; r < 4; ++r) {
            int s = qbase + w * 16 + quad * 4 + r;
            Og[(size_t)(b * 2048 + s) * 1024 + h * 64 + dt * 16 + ln] =
                f2bf(oacc[dt][r] * rden[r]);
        }
}

extern "C" void kernel_launch(void* const* d_in, const int* in_sizes, int n_in,
                              void* d_out, int out_size, void* d_ws, size_t ws_size,
                              hipStream_t stream) {
    const float* x     = (const float*)d_in[0];
    const float* w_qkv = (const float*)d_in[2];
    const float* w_out = (const float*)d_in[3];
    char* ws = (char*)d_ws;

    unsigned short* xb    = (unsigned short*)(ws);                      //  8 MB
    unsigned short* wqkvT = (unsigned short*)(ws + (size_t)(8 << 20));  //  6 MB
    unsigned short* woutT = (unsigned short*)(ws + (size_t)(14 << 20)); //  2 MB
    unsigned short* Qg    = (unsigned short*)(ws + (size_t)(16 << 20)); //  8 MB
    unsigned short* Kg    = (unsigned short*)(ws + (size_t)(24 << 20)); //  8 MB (flash K over-prefetch -> Vt, read-only)
    unsigned short* Vt    = (unsigned short*)(ws + (size_t)(32 << 20)); //  8 MB (flash V over-prefetch -> Og, read-only)
    unsigned short* Og    = (unsigned short*)(ws + (size_t)(40 << 20)); //  8 MB
    float2*         rope  = (float2*)(ws + (size_t)(48 << 20));         // 512 KB

    k_prep<<<2304, 256, 0, stream>>>(x, w_qkv, w_out, xb, wqkvT, woutT, rope);
    k_gemm_qkv<<<dim3(12, 16), 512, 0, stream>>>(xb, wqkvT, rope, Qg, Kg, Vt);
    k_flash<<<1024, 256, 0, stream>>>(Qg, Kg, Vt, Og);
    k_gemm_out<<<dim3(8, 32), 256, 0, stream>>>(Og, woutT, (float*)d_out);
}

// Round 9
// 182.615 us; speedup vs baseline: 1.0386x; 1.0386x over previous
//
#include <hip/hip_runtime.h>
#include <hip/hip_bf16.h>
#include <stdint.h>

typedef float v4f __attribute__((ext_vector_type(4)));
typedef short v8s __attribute__((ext_vector_type(8)));
typedef short v4s __attribute__((ext_vector_type(4)));

#define LOG2E 1.44269504088896f
#define QSCALE (0.125f * LOG2E)   // fold softmax log2-domain into Q pre-scale
#define SOFTMAX_OFF 16.0f         // fixed softmax offset (exact; cancels in O/l)

__device__ __forceinline__ unsigned short f2bf(float f) {
    unsigned int u = __float_as_uint(f);
    u += 0x7fffu + ((u >> 16) & 1u);          // RTNE
    return (unsigned short)(u >> 16);
}

#define LDS_FENCE() __builtin_amdgcn_fence(__ATOMIC_ACQ_REL, "workgroup")

// async global->LDS, 16B per lane, LDS dest = wave-uniform base + lane*16
__device__ __forceinline__ void gload_lds16(const unsigned short* g, unsigned short* s) {
    __builtin_amdgcn_global_load_lds(
        (const __attribute__((address_space(1))) unsigned int*)g,
        (__attribute__((address_space(3))) unsigned int*)s, 16, 0, 0);
}

#define BAR()      asm volatile("s_barrier" ::: "memory")
#define VMWAIT(N)  asm volatile("s_waitcnt vmcnt(" #N ")" ::: "memory")

// ---------------- prep: cast + rope table + both weight transposes ----------------
// r9: transpose blocks use float4 loads, padded [64][88] tile (176B stride: 2-way max
// both phases), and v8s vectorized stores (2 iters vs 16 scalar).
__global__ void k_prep(const float* __restrict__ x,
                       const float* __restrict__ w_qkv,
                       const float* __restrict__ w_out,
                       unsigned short* __restrict__ xb,
                       unsigned short* __restrict__ wqkvT,
                       unsigned short* __restrict__ woutT,
                       float2* __restrict__ rope) {
    __shared__ __align__(16) unsigned short tile[64][88];
    int id = blockIdx.x, t = threadIdx.x;
    if (id < 1024) {
        int base = id * 256 + t;
#pragma unroll
        for (int k = 0; k < 4; ++k) {
            int i = base + k * 262144;
            float4 v = ((const float4*)x)[i];
            ushort4 o;
            o.x = f2bf(v.x); o.y = f2bf(v.y); o.z = f2bf(v.z); o.w = f2bf(v.w);
            ((ushort4*)xb)[i] = o;
        }
        return;
    }
    id -= 1024;
    if (id < 256) {
        int idx = id * 256 + t;                    // 65536 = 2048 s x 32 d
        int s = idx >> 5, d = idx & 31;
        float inv = __expf(-(float)d * 0.28782313662425572f);  // 10000^(-d/32)
        float sn, cs;
        sincosf((float)s * inv, &sn, &cs);
        rope[idx] = make_float2(cs, sn);
        return;
    }
    id -= 256;
    const float* src; unsigned short* dst; int N, kb, nb;
    if (id < 768) { src = w_qkv; dst = wqkvT; N = 3072; nb = (id % 48) * 64; kb = (id / 48) * 64; }
    else { id -= 768; src = w_out; dst = woutT; N = 1024; nb = (id % 16) * 64; kb = (id / 16) * 64; }
    const int K = 1024;
#pragma unroll
    for (int i = 0; i < 4; ++i) {
        int e = t + i * 256;                       // 1024 float4 quads: 64k x 16 groups
        int k_l = e >> 4, n4 = (e & 15) * 4;
        float4 v = *(const float4*)&src[(size_t)(kb + k_l) * N + nb + n4];
        tile[n4 + 0][k_l] = f2bf(v.x);
        tile[n4 + 1][k_l] = f2bf(v.y);
        tile[n4 + 2][k_l] = f2bf(v.z);
        tile[n4 + 3][k_l] = f2bf(v.w);
    }
    __syncthreads();
#pragma unroll
    for (int i = 0; i < 2; ++i) {
        int c = t + i * 256;                       // 512 v8s chunks: 64 rows x 8
        int n_l = c >> 3, kc = (c & 7) * 8;
        v8s val = *(const v8s*)&tile[n_l][kc];
        *(v8s*)&dst[(size_t)(nb + n_l) * K + kb + kc] = val;
    }
}

// ------------- QKV GEMM: 256x256 tile, BK=64, 8 waves, 8-phase (unchanged from r8) ----
__global__ __launch_bounds__(512, 2) void k_gemm_qkv(
    const unsigned short* __restrict__ A,
    const unsigned short* __restrict__ Bt,
    const float2* __restrict__ rope,
    unsigned short* __restrict__ Qg,
    unsigned short* __restrict__ Kg,
    unsigned short* __restrict__ Vt) {
    const int K = 1024;
    __shared__ __align__(16) union {
        struct { unsigned short Ab[2][256 * 64], Bb[2][256 * 64]; } g;  // 128 KB
        unsigned short vt[4][64][264];                                  // 132 KB V-transpose
        unsigned short qk[8][128][66];                                  // 132 KB Q/K transpose
    } sm;
    const int t = threadIdx.x;
    const int w = t >> 6, l = t & 63, quad = l >> 4, ln = l & 15;
    const int wr = w >> 2, wc = w & 3;            // wave grid 2M x 4N, 128x64 per wave
    const int lid = blockIdx.y * 12 + blockIdx.x;
    const int swzb = (lid & 7) * 24 + (lid >> 3); // XCD swizzle, bijective (192%8==0)
    const int mb = (swzb / 12) * 256, nb = (swzb % 12) * 256;
    const int lxr = l >> 3;
    const int swz = ((l & 7) ^ lxr) * 8;          // pre-swizzled src col (ushorts)

    v4f acc[8][4];
#pragma unroll
    for (int i = 0; i < 8; ++i)
#pragma unroll
        for (int j = 0; j < 4; ++j) acc[i][j] = (v4f){0.f, 0.f, 0.f, 0.f};

    auto stageHT = [&](const unsigned short* src, int grow, int k0, unsigned short* lds) {
#pragma unroll
        for (int c = 0; c < 2; ++c) {
            int r0 = w * 16 + c * 8;
            gload_lds16(src + (size_t)(grow + r0 + lxr) * K + k0 + swz, lds + r0 * 64);
        }
    };
    auto frag = [&](const unsigned short* base, int row, int g16) -> v8s {
        return *(const v8s*)&base[row * 64 + ((g16 ^ (row & 7)) << 3)];
    };

    v8s aF[4][2], bF0[2][2], bF1[2][2];
    auto readA = [&](const unsigned short* Ap, int ih) {
#pragma unroll
        for (int ii = 0; ii < 4; ++ii) {
            int row = wr * 128 + (ih * 4 + ii) * 16 + ln;
#pragma unroll
            for (int kh = 0; kh < 2; ++kh) aF[ii][kh] = frag(Ap, row, kh * 4 + quad);
        }
    };
    auto readB = [&](const unsigned short* Bp, int jh, v8s (&bF)[2][2]) {
#pragma unroll
        for (int jj = 0; jj < 2; ++jj) {
            int row = wc * 64 + (jh * 2 + jj) * 16 + ln;
#pragma unroll
            for (int kh = 0; kh < 2; ++kh) bF[jj][kh] = frag(Bp, row, kh * 4 + quad);
        }
    };
    auto mfma16 = [&](v8s (&bF)[2][2], int ih, int jh) {
        __builtin_amdgcn_s_setprio(1);
#pragma unroll
        for (int ii = 0; ii < 4; ++ii)
#pragma unroll
            for (int jj = 0; jj < 2; ++jj) {
                v4f* ac = &acc[ih * 4 + ii][jh * 2 + jj];
                *ac = __builtin_amdgcn_mfma_f32_16x16x32_bf16(aF[ii][0], bF[jj][0], *ac, 0, 0, 0);
                *ac = __builtin_amdgcn_mfma_f32_16x16x32_bf16(aF[ii][1], bF[jj][1], *ac, 0, 0, 0);
            }
        __builtin_amdgcn_s_setprio(0);
    };

    const unsigned short* Ap0 = &sm.g.Ab[0][0];
    const unsigned short* Ap1 = &sm.g.Ab[1][0];
    const unsigned short* Bp0 = &sm.g.Bb[0][0];
    const unsigned short* Bp1 = &sm.g.Bb[1][0];

    stageHT(A,  mb,       0,  &sm.g.Ab[0][0]);
    stageHT(A,  mb + 128, 0,  &sm.g.Ab[0][128 * 64]);
    stageHT(Bt, nb,       0,  &sm.g.Bb[0][0]);
    stageHT(Bt, nb + 128, 0,  &sm.g.Bb[0][128 * 64]);
    stageHT(Bt, nb,       64, &sm.g.Bb[1][0]);
    stageHT(Bt, nb + 128, 64, &sm.g.Bb[1][128 * 64]);
    VMWAIT(4);
    BAR();

    for (int it = 0; it < 8; ++it) {
        const int c1k = (2 * it + 1) * 64, n0k = (2 * it + 2) * 64, n1k = (2 * it + 3) * 64;
        const bool pre = it < 7;
        readA(Ap0, 0); readB(Bp0, 0, bF0);
        stageHT(A, mb, c1k, &sm.g.Ab[1][0]);
        BAR();
        mfma16(bF0, 0, 0);
        BAR();
        readB(Bp0, 1, bF1);
        stageHT(A, mb + 128, c1k, &sm.g.Ab[1][128 * 64]);
        BAR();
        mfma16(bF1, 0, 1);
        BAR();
        readA(Ap0, 1);
        if (pre) stageHT(Bt, nb, n0k, &sm.g.Bb[0][0]);
        BAR();
        mfma16(bF0, 1, 0);
        BAR();
        if (pre) stageHT(Bt, nb + 128, n0k, &sm.g.Bb[0][128 * 64]);
        BAR();
        mfma16(bF1, 1, 1);
        if (pre) VMWAIT(4); else VMWAIT(0);
        BAR();
        readA(Ap1, 0); readB(Bp1, 0, bF0);
        if (pre) stageHT(A, mb, n0k, &sm.g.Ab[0][0]);
        BAR();
        mfma16(bF0, 0, 0);
        BAR();
        readB(Bp1, 1, bF1);
        if (pre) stageHT(A, mb + 128, n0k, &sm.g.Ab[0][128 * 64]);
        BAR();
        mfma16(bF1, 0, 1);
        BAR();
        readA(Ap1, 1);
        if (pre) stageHT(Bt, nb, n1k, &sm.g.Bb[1][0]);
        BAR();
        mfma16(bF0, 1, 0);
        BAR();
        if (pre) stageHT(Bt, nb + 128, n1k, &sm.g.Bb[1][128 * 64]);
        BAR();
        mfma16(bF1, 1, 1);
        if (pre) VMWAIT(4);
        BAR();
    }

    if (nb >= 2048) {                              // ---- V: LDS transpose epilogue
        __syncthreads();
#pragma unroll
        for (int i = 0; i < 8; ++i)
#pragma unroll
            for (int j = 0; j < 4; ++j) {
                int d = j * 16 + ln;
                int s0 = wr * 128 + i * 16 + quad * 4;
                ushort4 pk;
                pk.x = f2bf(acc[i][j][0]); pk.y = f2bf(acc[i][j][1]);
                pk.z = f2bf(acc[i][j][2]); pk.w = f2bf(acc[i][j][3]);
                *(ushort4*)&sm.vt[wc][d][s0] = pk;
            }
        __syncthreads();
        const int hbase = (nb & 1023) >> 6;
        const int b = mb >> 11, sbase = mb & 2047;
#pragma unroll
        for (int i = 0; i < 16; ++i) {
            int c = t + i * 512;                   // 8192 chunks of 16B
            int h2 = c >> 11, dd = (c >> 5) & 63, off = (c & 31) * 8;
            v8s val = *(const v8s*)&sm.vt[h2][dd][off];
            *(v8s*)(Vt + ((size_t)((b * 16 + hbase + h2) * 64 + dd) * 2048 + sbase + off)) = val;
        }
        return;
    }

    // ---- Q/K: rope in-register -> wave-private LDS tile -> coalesced 16B stores
    const int nbw = nb + wc * 64;
    const int region = nbw >> 10;                  // 0=Q, 1=K
    const int h = (nbw & 1023) >> 6;
    unsigned short* dst = region == 0 ? Qg : Kg;
    const float scale = region == 0 ? QSCALE : 1.0f;
    unsigned short* qkw = &sm.qk[w][0][0];         // wave-private [128][66]
#pragma unroll
    for (int jj = 0; jj < 2; ++jj) {
        const float2* rp = rope + jj * 16 + ln;
#pragma unroll
        for (int i = 0; i < 8; ++i)
#pragma unroll
            for (int r = 0; r < 4; ++r) {
                int lr = i * 16 + quad * 4 + r;
                int s = (mb + wr * 128 + lr) & 2047;
                float2 cs = rp[s * 32];
                float t1 = acc[i][jj][r], t2 = acc[i][jj + 2][r];
                qkw[lr * 66 + jj * 16 + ln]      = f2bf((t1 * cs.x - t2 * cs.y) * scale);
                qkw[lr * 66 + jj * 16 + ln + 32] = f2bf((t2 * cs.x + t1 * cs.y) * scale);
            }
    }
    LDS_FENCE();
    const int row0 = mb + wr * 128;
    const int bb = row0 >> 11, s0 = row0 & 2047;
    unsigned short* gbase = dst + ((size_t)(bb * 16 + h) * 2048 + s0) * 64;
#pragma unroll
    for (int itn = 0; itn < 16; ++itn) {
        int c = itn * 64 + l;
        int lr = c >> 3, off = (c & 7) * 8;
        v8s val = *(const v8s*)&qkw[lr * 66 + off];
        *(v8s*)(gbase + (size_t)lr * 64 + off) = val;
    }
}

// ------------- output projection GEMM v2: 64x128 tiles, 512 blocks (2/CU), BK=64 ------
// r9 rewrite: old version ran 256 blocks = 1 block/CU (4 waves!) with an unswizzled
// 32-short-row LDS layout (same 8-way-conflict pattern qkv had pre-r2).  Now: 2x
// concurrency + qkv's proven 64-short-row XOR-swizzle layout + 3-buf counted vmcnt
// (6 loads/stage -> KEEP6).
__global__ __launch_bounds__(256) void k_gemm_out(
    const unsigned short* __restrict__ A,      // Og [4096][1024]
    const unsigned short* __restrict__ Bt,     // woutT [1024][1024]
    float* __restrict__ C) {
    const int K = 1024, N = 1024;
    __shared__ __align__(16) unsigned short Ab[3][64 * 64];    // 24 KB
    __shared__ __align__(16) unsigned short Bb[3][128 * 64];   // 48 KB  (72 KB total)
    const int t = threadIdx.x;
    const int w = t >> 6, l = t & 63, quad = l >> 4, ln = l & 15;
    const int wm = (w >> 1) * 32, wn = (w & 1) * 64;
    const int mb = blockIdx.y * 64, nb = blockIdx.x * 128;
    const int lxr = l >> 3;
    const int swz = ((l & 7) ^ lxr) * 8;

    v4f acc[2][4];
#pragma unroll
    for (int i = 0; i < 2; ++i)
#pragma unroll
        for (int j = 0; j < 4; ++j) acc[i][j] = (v4f){0.f, 0.f, 0.f, 0.f};

    auto stage = [&](int buf, int k0) {
#pragma unroll
        for (int c = 0; c < 2; ++c) {              // A: 64 rows
            int r0 = w * 16 + c * 8;
            gload_lds16(A + (size_t)(mb + r0 + lxr) * K + k0 + swz, &Ab[buf][r0 * 64]);
        }
#pragma unroll
        for (int c = 0; c < 4; ++c) {              // B: 128 rows
            int r0 = w * 32 + c * 8;
            gload_lds16(Bt + (size_t)(nb + r0 + lxr) * K + k0 + swz, &Bb[buf][r0 * 64]);
        }
    };
    auto frag = [&](const unsigned short* base, int row, int g16) -> v8s {
        return *(const v8s*)&base[row * 64 + ((g16 ^ (row & 7)) << 3)];
    };

    stage(0, 0);
    stage(1, 64);
    int cur = 0, nxt = 2;
    for (int itk = 0; itk < 16; ++itk) {
        if (itk < 15) VMWAIT(6);                   // oldest stage landed; newest in flight
        else          VMWAIT(0);
        BAR();
        if (itk + 2 < 16) {
            stage(nxt, (itk + 2) * 64);
            nxt = nxt == 2 ? 0 : nxt + 1;
        }
        v8s af[2][2], bf[4][2];
#pragma unroll
        for (int i = 0; i < 2; ++i)
#pragma unroll
            for (int kh = 0; kh < 2; ++kh)
                af[i][kh] = frag(&Ab[cur][0], wm + i * 16 + ln, kh * 4 + quad);
#pragma unroll
        for (int j = 0; j < 4; ++j)
#pragma unroll
            for (int kh = 0; kh < 2; ++kh)
                bf[j][kh] = frag(&Bb[cur][0], wn + j * 16 + ln, kh * 4 + quad);
#pragma unroll
        for (int i = 0; i < 2; ++i)
#pragma unroll
            for (int j = 0; j < 4; ++j) {
                acc[i][j] = __builtin_amdgcn_mfma_f32_16x16x32_bf16(af[i][0], bf[j][0], acc[i][j], 0, 0, 0);
                acc[i][j] = __builtin_amdgcn_mfma_f32_16x16x32_bf16(af[i][1], bf[j][1], acc[i][j], 0, 0, 0);
            }
        cur = cur == 2 ? 0 : cur + 1;
    }

#pragma unroll
    for (int i = 0; i < 2; ++i) {
        int r0 = mb + wm + i * 16 + quad * 4;
#pragma unroll
        for (int j = 0; j < 4; ++j) {
            int c0 = nb + wn + j * 16 + ln;
#pragma unroll
            for (int r = 0; r < 4; ++r)
                C[(size_t)(r0 + r) * N + c0] = acc[i][j][r];
        }
    }
}

// ------------- causal flash attention, v14: in-register P, bias-folded exp ----------
// v12 PV form (direct b64 V-reads; v13's b128+select compiled to identical code).
// SOFTMAX_OFF folded into the QK MFMA C-init (sc starts at -16) - kills 16 subs/iter.
__global__ __launch_bounds__(256, 4) void k_flash(
    const unsigned short* __restrict__ Qg,   // [BH][S][64], scaled 0.125*log2e
    const unsigned short* __restrict__ Kg,   // [BH][S][64]
    const unsigned short* __restrict__ Vt,   // [BH][64][S]
    unsigned short* __restrict__ Og) {       // [B*S][1024]
    __shared__ __align__(16) unsigned short Kb[2][64 * 64];
    __shared__ __align__(16) unsigned short Vb[2][64 * 64];

    const int id = blockIdx.x;
    const int xcd = id & 7, slot = id >> 3;
    const int bh = xcd * 4 + (slot & 3);
    const int qt = 31 - (slot >> 2);                 // heavy tiles first
    const int qbase = qt * 64;
    const int nit = qt + 1;

    const int t = threadIdx.x, w = t >> 6, l = t & 63, quad = l >> 4, ln = l & 15;
    const int b = bh >> 4, h = bh & 15;

    const unsigned short* Qp = Qg + (size_t)bh * 2048 * 64;
    const unsigned short* Kp = Kg + (size_t)bh * 2048 * 64;
    const unsigned short* Vp = Vt + (size_t)bh * 64 * 2048;

    unsigned kst[2], vst[2];
    int cchunk = l & 7, rloc = l >> 3;
#pragma unroll
    for (int j = 0; j < 2; ++j) {
        int c = w + j * 4;
        int rr = c * 8 + rloc;
        int g = (cchunk + rr) & 7;
        kst[j] = (unsigned)(rr * 64 + g * 8);
        vst[j] = (unsigned)(rr * 2048 + g * 8);
    }
    const int c0 = ((quad - ln) & 7) * 8;            // K-row granule decode (d 0..31)
    const int c1 = ((quad + 4 - ln) & 7) * 8;        // (d 32..63)
    int vcol[4];
#pragma unroll
    for (int kt = 0; kt < 4; ++kt)
        vcol[kt] = (((kt * 2 + (quad >> 1) - ln) & 7) << 3) + (quad & 1) * 4;
    const v4s ones4 = {0x3F80, 0x3F80, 0x3F80, 0x3F80};

    const int qrow = qbase + w * 16 + ln;
    v8s qf0 = *(const v8s*)(Qp + (size_t)qrow * 64 + quad * 8);
    v8s qf1 = *(const v8s*)(Qp + (size_t)qrow * 64 + quad * 8 + 32);

    v4f oacc[5];
#pragma unroll
    for (int dt = 0; dt < 5; ++dt) oacc[dt] = (v4f){0.f, 0.f, 0.f, 0.f};

    auto stage = [&](int buf, int kvb) {
        const unsigned short* kg = Kp + (size_t)kvb * 64;
        const unsigned short* vg = Vp + kvb;
#pragma unroll
        for (int j = 0; j < 2; ++j) {
            int c = w + j * 4;
            gload_lds16(kg + kst[j], &Kb[buf][c * 512]);
            gload_lds16(vg + vst[j], &Vb[buf][c * 512]);
        }
    };

    auto compute = [&](int buf, int it) {
        v4f sc[4];
#pragma unroll
        for (int kt = 0; kt < 4; ++kt) {
            int row = kt * 16 + ln;
            v8s k0 = *(const v8s*)&Kb[buf][row * 64 + c0];
            v8s k1 = *(const v8s*)&Kb[buf][row * 64 + c1];
            sc[kt] = (v4f){-SOFTMAX_OFF, -SOFTMAX_OFF, -SOFTMAX_OFF, -SOFTMAX_OFF};
            sc[kt] = __builtin_amdgcn_mfma_f32_16x16x32_bf16(k0, qf0, sc[kt], 0, 0, 0);
            sc[kt] = __builtin_amdgcn_mfma_f32_16x16x32_bf16(k1, qf1, sc[kt], 0, 0, 0);
        }
        if (it == qt) {                              // causal: k = kt*16+quad*4+r, q = w*16+ln
            int qg = w * 16 + ln;
#pragma unroll
            for (int kt = 0; kt < 4; ++kt) {
                int kv = kt * 16 + quad * 4;
#pragma unroll
                for (int r = 0; r < 4; ++r)
                    if (kv + r > qg) sc[kt][r] = -1e30f;
            }
        }
#pragma unroll
        for (int kt = 0; kt < 4; ++kt)
#pragma unroll
            for (int r = 0; r < 4; ++r)
                sc[kt][r] = exp2f(sc[kt][r]);        // offset pre-folded into C-init

        v4s pa[4];
#pragma unroll
        for (int kt = 0; kt < 4; ++kt) {
            union { __hip_bfloat162 hh; unsigned int u; } p01, p23;
            p01.hh = __float22bfloat162_rn(make_float2(sc[kt][0], sc[kt][1]));
            p23.hh = __float22bfloat162_rn(make_float2(sc[kt][2], sc[kt][3]));
            union { v4s v; unsigned int u[2]; } pk;
            pk.u[0] = p01.u; pk.u[1] = p23.u;
            pa[kt] = pk.v;
        }
        __builtin_amdgcn_s_setprio(1);
#pragma unroll
        for (int dt = 0; dt < 4; ++dt) {
            int rowb = (dt * 16 + ln) * 64;
#pragma unroll
            for (int kt = 0; kt < 4; ++kt) {
                v4s vf = *(const v4s*)&Vb[buf][rowb + vcol[kt]];
                oacc[dt] = __builtin_amdgcn_mfma_f32_16x16x16bf16_1k(pa[kt], vf, oacc[dt], 0, 0, 0);
            }
        }
#pragma unroll
        for (int kt = 0; kt < 4; ++kt)
            oacc[4] = __builtin_amdgcn_mfma_f32_16x16x16bf16_1k(pa[kt], ones4, oacc[4], 0, 0, 0);
        __builtin_amdgcn_s_setprio(0);
    };

    stage(0, 0);
    for (int it = 0;;) {
        const int buf = it & 1;
        stage(buf ^ 1, (it + 1) * 64);   // prefetch next tile (over-reads are in-workspace)
        VMWAIT(4);                       // wait own stage(buf); stage(buf^1) stays in flight
        BAR();
        compute(buf, it);
        if (++it >= nit) break;
        BAR();
    }

    float rden[4];
#pragma unroll
    for (int r = 0; r < 4; ++r) rden[r] = 1.f / oacc[4][r];
#pragma unroll
    for (int dt = 0; dt < 4; ++dt)
#pragma unroll
        for (int r = 0; r < 4; ++r) {
            int s = qbase + w * 16 + quad * 4 + r;
            Og[(size_t)(b * 2048 + s) * 1024 + h * 64 + dt * 16 + ln] =
                f2bf(oacc[dt][r] * rden[r]);
        }
}

extern "C" void kernel_launch(void* const* d_in, const int* in_sizes, int n_in,
                              void* d_out, int out_size, void* d_ws, size_t ws_size,
                              hipStream_t stream) {
    const float* x     = (const float*)d_in[0];
    const float* w_qkv = (const float*)d_in[2];
    const float* w_out = (const float*)d_in[3];
    char* ws = (char*)d_ws;

    unsigned short* xb    = (unsigned short*)(ws);                      //  8 MB
    unsigned short* wqkvT = (unsigned short*)(ws + (size_t)(8 << 20));  //  6 MB
    unsigned short* woutT = (unsigned short*)(ws + (size_t)(14 << 20)); //  2 MB
    unsigned short* Qg    = (unsigned short*)(ws + (size_t)(16 << 20)); //  8 MB
    unsigned short* Kg    = (unsigned short*)(ws + (size_t)(24 << 20)); //  8 MB (flash K over-prefetch -> Vt, read-only)
    unsigned short* Vt    = (unsigned short*)(ws + (size_t)(32 << 20)); //  8 MB (flash V over-prefetch -> Og, read-only)
    unsigned short* Og    = (unsigned short*)(ws + (size_t)(40 << 20)); //  8 MB
    float2*         rope  = (float2*)(ws + (size_t)(48 << 20));         // 512 KB

    k_prep<<<2304, 256, 0, stream>>>(x, w_qkv, w_out, xb, wqkvT, woutT, rope);
    k_gemm_qkv<<<dim3(12, 16), 512, 0, stream>>>(xb, wqkvT, rope, Qg, Kg, Vt);
    k_flash<<<1024, 256, 0, stream>>>(Qg, Kg, Vt, Og);
    k_gemm_out<<<dim3(8, 64), 256, 0, stream>>>(Og, woutT, (float*)d_out);
}